// Round 3
// baseline (215.286 us; speedup 1.0000x reference)
//
#include <hip/hip_runtime.h>
#include <cstdint>

// Linear-chain CRF log-partition, B=64, T=4096, S=64.
// R8: occupancy + launch-count round.
//  - R7 post-mortem: compiler sank the upfront em burst (VGPR 112, not ~214);
//    phase1 still latency-bound at ~5 waves/CU (block lifetime 18.5us vs ~3us
//    model). Residency is per-BLOCK limited -> pack 4 chunk-group waves per
//    256-thread block (928 blocks, per-wave code unchanged, disjoint LDS
//    slices). 4x waves/CU -> 4x MLP.
//  - Non-phase1 residue grew 51->79->84us as kernel count went 2->3; phase2/3
//    never in top-5 (<46us each). Fold phase3 into phase2 (one block/batch,
//    1024 threads, in-block deterministic reduce) -> 2 launches total.

#define B_    64
#define T_    4096
#define S_    64
#define L_    9
#define NC_   455                 // 455*9 = 4095 = T_-1
#define WPB_  29                  // 16-chain wave-groups per batch (29*16=464)
#define CPB_  464
#define LOG2E 1.44269504088896340736f

typedef float  f32x4  __attribute__((ext_vector_type(4)));
typedef __bf16 bf16x8 __attribute__((ext_vector_type(8)));
union U4B { uint4 u; bf16x8 b; };

__global__ __launch_bounds__(256, 8) void crf_phase1(
    const float* __restrict__ scores,      // (B,T,S)
    const float* __restrict__ transition,  // (S,S) [from,to]
    float* __restrict__ Ybuf, float* __restrict__ Zbuf, float* __restrict__ Lz)
{
    __shared__ float tb[4][16][68];        // per-wave transpose slice
    const int wv   = threadIdx.x >> 6;     // wave within block
    const int wid  = blockIdx.x * 4 + wv;  // global wave id (== R7 blockIdx)
    const bool bwd = wid >= (B_ * WPB_);   // blocks 0..463 fwd, 464..927 bwd
    const int wl   = bwd ? wid - B_ * WPB_ : wid;
    const int b    = wl / WPB_, wg = wl % WPB_;
    const int lane = threadIdx.x & 63, g = lane >> 4, l = lane & 15;

    // A-side emission pointer: chain = local row l, states 8g.. contiguous
    int cl = 16 * wg + l; if (cl > NC_ - 1) cl = NC_ - 1;
    const float* ap = scores + ((size_t)b * T_ + L_ * cl + (bwd ? L_ : 0)) * S_ + 8 * g;

    auto ldq = [&](int idx, f32x4* q) {
        const float* p = ap + (ptrdiff_t)idx * S_;
        q[0] = *(const f32x4*)p;        q[1] = *(const f32x4*)(p + 4);
        q[2] = *(const f32x4*)(p + 32); q[3] = *(const f32x4*)(p + 36);
    };

    // issue all emission loads up front (compiler may reschedule; the MLP
    // lever this round is 4 waves/block, not the burst)
    f32x4 em[L_][4];
    if (!bwd) {
        #pragma unroll
        for (int r = 1; r < L_; ++r) ldq(r, em[r - 1]);       // rows t0+1..t0+8
    } else {
        #pragma unroll
        for (int i = 0; i < L_; ++i) ldq(-i, em[i]);          // rows t0+L..t0+1
    }

    // ---- E fragments in registers: fwd B[k][n]=exp(T[k][n]); bwd =exp(T[n][k])
    bf16x8 BE[2][4];
    #pragma unroll
    for (int kb = 0; kb < 2; ++kb)
    #pragma unroll
    for (int nt = 0; nt < 4; ++nt) {
        bf16x8 t;
        #pragma unroll
        for (int dd = 0; dd < 4; ++dd) {
            int k0 = 32 * kb + 8 * g + 2 * dd, n = 16 * nt + l;
            float e0, e1;
            if (!bwd) { e0 = transition[k0 * 64 + n]; e1 = transition[(k0 + 1) * 64 + n]; }
            else      { e0 = transition[n * 64 + k0]; e1 = transition[n * 64 + k0 + 1]; }
            t[2 * dd]     = (__bf16)exp2f(e0 * LOG2E);
            t[2 * dd + 1] = (__bf16)exp2f(e1 * LOG2E);
        }
        BE[kb][nt] = t;
    }

    f32x4 acc[4];
    int   Lt[4] = {0, 0, 0, 0};

    auto mfma8 = [&](bf16x8 A0, bf16x8 A1) {
        #pragma unroll
        for (int nt = 0; nt < 4; ++nt) {
            f32x4 z4 = {0.f, 0.f, 0.f, 0.f};
            z4      = __builtin_amdgcn_mfma_f32_16x16x32_bf16(A0, BE[0][nt], z4, 0, 0, 0);
            acc[nt] = __builtin_amdgcn_mfma_f32_16x16x32_bf16(A1, BE[1][nt], z4, 0, 0, 0);
        }
    };
    auto renorm = [&]() {
        #pragma unroll
        for (int r = 0; r < 4; ++r) {
            float m = fmaxf(fmaxf(acc[0][r], acc[1][r]), fmaxf(acc[2][r], acc[3][r]));
            m = fmaxf(m, __shfl_xor(m, 1, 64));
            m = fmaxf(m, __shfl_xor(m, 2, 64));
            m = fmaxf(m, __shfl_xor(m, 4, 64));
            m = fmaxf(m, __shfl_xor(m, 8, 64));
            int ex = (int)(__float_as_uint(m) >> 23) - 127;
            float sc = __uint_as_float((unsigned)(127 - ex) << 23);   // exact 2^-ex
            Lt[r] += ex;
            #pragma unroll
            for (int nt = 0; nt < 4; ++nt) acc[nt][r] *= sc;
        }
    };
    // transpose acc (C: chain 4g+r, state 16nt+l) -> per-lane A rows, * em, pack
    auto xposeA = [&](const f32x4& c0, const f32x4& c1,
                      const f32x4& c2, const f32x4& c3, bf16x8& A0, bf16x8& A1) {
        #pragma unroll
        for (int nt = 0; nt < 4; ++nt)
            #pragma unroll
            for (int r = 0; r < 4; ++r)
                tb[wv][4 * g + r][16 * nt + l] = acc[nt][r];
        __builtin_amdgcn_s_waitcnt(0xC07F);        // lgkmcnt(0) only, vmcnt open
        __builtin_amdgcn_wave_barrier();
        const float* rowp = &tb[wv][l][8 * g];
        f32x4 x0 = *(const f32x4*)rowp;
        f32x4 x1 = *(const f32x4*)(rowp + 4);
        f32x4 x2 = *(const f32x4*)(rowp + 32);
        f32x4 x3 = *(const f32x4*)(rowp + 36);
        #pragma unroll
        for (int d = 0; d < 4; ++d) {
            A0[d]     = (__bf16)(x0[d] * exp2f(c0[d] * LOG2E));
            A0[d + 4] = (__bf16)(x1[d] * exp2f(c1[d] * LOG2E));
            A1[d]     = (__bf16)(x2[d] * exp2f(c2[d] * LOG2E));
            A1[d + 4] = (__bf16)(x3[d] * exp2f(c3[d] * LOG2E));
        }
    };

    if (!bwd) {
        // y'_c = 1^T E d1 E d2 ... d(L-1) E  (em rows t0+1..t0+L-1; dL in phase2)
        { U4B t; t.u = make_uint4(0x3F803F80u, 0x3F803F80u, 0x3F803F80u, 0x3F803F80u);
          mfma8(t.b, t.b); }                       // tt=0: A = ones
        #pragma unroll
        for (int tt = 1; tt < L_; ++tt) {
            f32x4* q = em[tt - 1];
            bf16x8 A0, A1;
            xposeA(q[0], q[1], q[2], q[3], A0, A1);
            mfma8(A0, A1);
            if ((tt & 3) == 3) renorm();
        }
        float* yb = Ybuf + ((size_t)(b * WPB_ + wg) << 10);
        #pragma unroll
        for (int nt = 0; nt < 4; ++nt)
            *(f32x4*)(yb + ((nt * 64 + lane) << 2)) = acc[nt];   // coalesced
    } else {
        // z_c = E d1 E d2 ... E dL * 1, rows consumed descending (L..1)
        {   // i=0: A = em(row t0+L) (z = ones)
            f32x4* q = em[0];
            bf16x8 A0, A1;
            #pragma unroll
            for (int d = 0; d < 4; ++d) {
                A0[d]     = (__bf16)exp2f(q[0][d] * LOG2E);
                A0[d + 4] = (__bf16)exp2f(q[1][d] * LOG2E);
                A1[d]     = (__bf16)exp2f(q[2][d] * LOG2E);
                A1[d + 4] = (__bf16)exp2f(q[3][d] * LOG2E);
            }
            mfma8(A0, A1);
        }
        #pragma unroll
        for (int i = 1; i < L_; ++i) {
            f32x4* q = em[i];
            bf16x8 A0, A1;
            xposeA(q[0], q[1], q[2], q[3], A0, A1);
            mfma8(A0, A1);
            if ((i & 3) == 3) renorm();
        }
        float* zb = Zbuf + ((size_t)(b * WPB_ + wg) << 10);
        #pragma unroll
        for (int nt = 0; nt < 4; ++nt)
            *(f32x4*)(zb + ((nt * 64 + lane) << 2)) = acc[nt];   // coalesced
        if (l == 0) {
            #pragma unroll
            for (int r = 0; r < 4; ++r)
                Lz[b * CPB_ + 16 * wg + 4 * g + r] = (float)Lt[r];
        }
    }
}

// ---------------------------------------------------------------------------
// phase2: rank-1 recombination + per-batch reduce, one block per batch.
// 16 waves stride the 29 chunk-groups; wave math identical to R7 phase2.
// p_c = sum_s y'_c[s] em_end_c[s] zn[s],  q_c = sum_s y'_c[s] em_end_c[s],
// term_c = log2 p_c - log2 q_c + Lz[c];  zn = z_{c+1} (esink for c=NC-1).
// In-block LDS reduce (deterministic) -> out[b]. No phase3 launch.
// ---------------------------------------------------------------------------
__global__ __launch_bounds__(1024) void crf_phase2(
    const float* __restrict__ scores, const float* __restrict__ source,
    const float* __restrict__ sink,
    const float* __restrict__ Ybuf, const float* __restrict__ Zbuf,
    const float* __restrict__ Lz, float* __restrict__ out)
{
    __shared__ float part[16];
    const int b = blockIdx.x;
    const int wv = threadIdx.x >> 6, lane = threadIdx.x & 63;
    const int q = lane >> 4, l = lane & 15;
    float acc = 0.f;

    float esk[4];
    #pragma unroll
    for (int nt = 0; nt < 4; ++nt) esk[nt] = exp2f(sink[16 * nt + l] * LOG2E);

    for (int wg = wv; wg < WPB_; wg += 16) {
        const int bw = b * WPB_ + wg;
        const float* Yb = Ybuf + ((size_t)bw << 10);
        const float* Zb = Zbuf + ((size_t)bw << 10);
        f32x4 y[4], z[4];
        #pragma unroll
        for (int nt = 0; nt < 4; ++nt) {
            y[nt] = *(const f32x4*)(Yb + ((nt * 64 + lane) << 2));
            z[nt] = *(const f32x4*)(Zb + ((nt * 64 + lane) << 2));
        }
        // em rows (end of each of this lane's 4 chunks), state 16nt+l
        float E2[4][4];
        #pragma unroll
        for (int r = 0; r < 4; ++r) {
            int c = 16 * wg + 4 * q + r; int cc = c < NC_ ? c : NC_ - 1;
            const float* er = scores + ((size_t)b * T_ + (size_t)L_ * cc + L_) * S_;
            #pragma unroll
            for (int nt = 0; nt < 4; ++nt)
                E2[r][nt] = exp2f(er[16 * nt + l] * LOG2E);
        }
        // z_next for r==3: chunk (q+1,0), from quad q+1 (or next group if q==3)
        float zn3[4];
        #pragma unroll
        for (int nt = 0; nt < 4; ++nt) zn3[nt] = __shfl(z[nt][0], lane + 16, 64);
        if (q == 3 && wg + 1 < WPB_) {
            const float* Zn = Zbuf + (((size_t)bw + 1) << 10);
            #pragma unroll
            for (int nt = 0; nt < 4; ++nt) zn3[nt] = Zn[(nt * 64 + l) << 2];
        }

        #pragma unroll
        for (int r = 0; r < 4; ++r) {
            int c = 16 * wg + 4 * q + r;
            float p = 0.f, qs = 0.f;
            #pragma unroll
            for (int nt = 0; nt < 4; ++nt) {
                float zz = (r < 3) ? z[nt][r + 1] : zn3[nt];
                if (c == NC_ - 1) zz = esk[nt];
                float ye = y[nt][r] * E2[r][nt];
                p  += ye * zz;
                qs += ye;
            }
            #pragma unroll
            for (int m = 1; m <= 8; m <<= 1) {
                p  += __shfl_xor(p, m, 64);
                qs += __shfl_xor(qs, m, 64);
            }
            if (l == 0 && c < NC_)
                acc += log2f(p) - log2f(qs) + Lz[b * CPB_ + c];
        }
        if (wg == 0 && q == 0) {    // a0 . z_0 term (wave 0 only)
            float s0 = 0.f;
            #pragma unroll
            for (int nt = 0; nt < 4; ++nt) {
                float a0 = exp2f((source[16 * nt + l]
                                  + scores[(size_t)b * T_ * S_ + 16 * nt + l]) * LOG2E);
                s0 += a0 * z[nt][0];
            }
            #pragma unroll
            for (int m = 1; m <= 8; m <<= 1) s0 += __shfl_xor(s0, m, 64);
            if (l == 0) acc += log2f(s0);
        }
    }
    #pragma unroll
    for (int m = 32; m >= 1; m >>= 1) acc += __shfl_xor(acc, m, 64);
    if (lane == 0) part[wv] = acc;
    __syncthreads();
    if (threadIdx.x == 0) {
        float s = 0.f;
        #pragma unroll
        for (int i = 0; i < 16; ++i) s += part[i];
        out[b] = 0.6931471805599453f * s + 4.158883083359672f;  // ln2*log2Z + ln64
    }
}

extern "C" void kernel_launch(void* const* d_in, const int* in_sizes, int n_in,
                              void* d_out, int out_size, void* d_ws, size_t ws_size,
                              hipStream_t stream) {
    (void)in_sizes; (void)n_in; (void)out_size; (void)ws_size;
    const float* scores     = (const float*)d_in[0];
    const float* transition = (const float*)d_in[1];
    const float* source     = (const float*)d_in[2];
    const float* sink       = (const float*)d_in[3];
    float* out = (float*)d_out;

    float* Ybuf = (float*)d_ws;                          // 64*29*1024 f32 (7.3 MB)
    float* Zbuf = Ybuf + (size_t)B_ * WPB_ * 1024;       // 7.3 MB
    float* Lz   = Zbuf + (size_t)B_ * WPB_ * 1024;       // 116 KB

    hipLaunchKernelGGL(crf_phase1, dim3(2 * B_ * WPB_ / 4), dim3(256), 0, stream,
                       scores, transition, Ybuf, Zbuf, Lz);
    hipLaunchKernelGGL(crf_phase2, dim3(B_), dim3(1024), 0, stream,
                       scores, source, sink, Ybuf, Zbuf, Lz, out);
}

// Round 4
// 172.436 us; speedup vs baseline: 1.2485x; 1.2485x over previous
//
#include <hip/hip_runtime.h>
#include <cstdint>

// Linear-chain CRF log-partition, B=64, T=4096, S=64.
// R9: fix the R8 spill.
//  - R8 post-mortem: __launch_bounds__(256,8) means 8 waves/EU -> 64-VGPR cap
//    -> full spill (VGPR_Count=32, WRITE_SIZE 15->228 MB, phase1 128us).
//    The 4-wave-block structure itself was right (occupancy rose to 35% even
//    while spilling). Correct bound: (256,4) -> 128 VGPR cap (code fits: R7
//    compiled to 112), 4 blocks/CU x 4 waves = 16 waves/CU.
//  - phase2 left byte-identical: residue (~85us) is stable across 3 different
//    phase2 structures and scales with NC (phase2 input bytes). Once phase1
//    drops below it, phase2 enters rocprof top-5 and next round gets its real
//    counters instead of inference.

#define B_    64
#define T_    4096
#define S_    64
#define L_    9
#define NC_   455                 // 455*9 = 4095 = T_-1
#define WPB_  29                  // 16-chain wave-groups per batch (29*16=464)
#define CPB_  464
#define LOG2E 1.44269504088896340736f

typedef float  f32x4  __attribute__((ext_vector_type(4)));
typedef __bf16 bf16x8 __attribute__((ext_vector_type(8)));
union U4B { uint4 u; bf16x8 b; };

__global__ __launch_bounds__(256, 4) void crf_phase1(
    const float* __restrict__ scores,      // (B,T,S)
    const float* __restrict__ transition,  // (S,S) [from,to]
    float* __restrict__ Ybuf, float* __restrict__ Zbuf, float* __restrict__ Lz)
{
    __shared__ float tb[4][16][68];        // per-wave transpose slice
    const int wv   = threadIdx.x >> 6;     // wave within block
    const int wid  = blockIdx.x * 4 + wv;  // global wave id
    const bool bwd = wid >= (B_ * WPB_);
    const int wl   = bwd ? wid - B_ * WPB_ : wid;
    const int b    = wl / WPB_, wg = wl % WPB_;
    const int lane = threadIdx.x & 63, g = lane >> 4, l = lane & 15;

    // A-side emission pointer: chain = local row l, states 8g.. contiguous
    int cl = 16 * wg + l; if (cl > NC_ - 1) cl = NC_ - 1;
    const float* ap = scores + ((size_t)b * T_ + L_ * cl + (bwd ? L_ : 0)) * S_ + 8 * g;

    auto ldq = [&](int idx, f32x4* q) {
        const float* p = ap + (ptrdiff_t)idx * S_;
        q[0] = *(const f32x4*)p;        q[1] = *(const f32x4*)(p + 4);
        q[2] = *(const f32x4*)(p + 32); q[3] = *(const f32x4*)(p + 36);
    };

    // issue all emission loads up front (compiler will keep as many live as
    // the 128-VGPR budget allows and sink the rest)
    f32x4 em[L_][4];
    if (!bwd) {
        #pragma unroll
        for (int r = 1; r < L_; ++r) ldq(r, em[r - 1]);       // rows t0+1..t0+8
    } else {
        #pragma unroll
        for (int i = 0; i < L_; ++i) ldq(-i, em[i]);          // rows t0+L..t0+1
    }

    // ---- E fragments in registers: fwd B[k][n]=exp(T[k][n]); bwd =exp(T[n][k])
    bf16x8 BE[2][4];
    #pragma unroll
    for (int kb = 0; kb < 2; ++kb)
    #pragma unroll
    for (int nt = 0; nt < 4; ++nt) {
        bf16x8 t;
        #pragma unroll
        for (int dd = 0; dd < 4; ++dd) {
            int k0 = 32 * kb + 8 * g + 2 * dd, n = 16 * nt + l;
            float e0, e1;
            if (!bwd) { e0 = transition[k0 * 64 + n]; e1 = transition[(k0 + 1) * 64 + n]; }
            else      { e0 = transition[n * 64 + k0]; e1 = transition[n * 64 + k0 + 1]; }
            t[2 * dd]     = (__bf16)exp2f(e0 * LOG2E);
            t[2 * dd + 1] = (__bf16)exp2f(e1 * LOG2E);
        }
        BE[kb][nt] = t;
    }

    f32x4 acc[4];
    int   Lt[4] = {0, 0, 0, 0};

    auto mfma8 = [&](bf16x8 A0, bf16x8 A1) {
        #pragma unroll
        for (int nt = 0; nt < 4; ++nt) {
            f32x4 z4 = {0.f, 0.f, 0.f, 0.f};
            z4      = __builtin_amdgcn_mfma_f32_16x16x32_bf16(A0, BE[0][nt], z4, 0, 0, 0);
            acc[nt] = __builtin_amdgcn_mfma_f32_16x16x32_bf16(A1, BE[1][nt], z4, 0, 0, 0);
        }
    };
    auto renorm = [&]() {
        #pragma unroll
        for (int r = 0; r < 4; ++r) {
            float m = fmaxf(fmaxf(acc[0][r], acc[1][r]), fmaxf(acc[2][r], acc[3][r]));
            m = fmaxf(m, __shfl_xor(m, 1, 64));
            m = fmaxf(m, __shfl_xor(m, 2, 64));
            m = fmaxf(m, __shfl_xor(m, 4, 64));
            m = fmaxf(m, __shfl_xor(m, 8, 64));
            int ex = (int)(__float_as_uint(m) >> 23) - 127;
            float sc = __uint_as_float((unsigned)(127 - ex) << 23);   // exact 2^-ex
            Lt[r] += ex;
            #pragma unroll
            for (int nt = 0; nt < 4; ++nt) acc[nt][r] *= sc;
        }
    };
    // transpose acc (C: chain 4g+r, state 16nt+l) -> per-lane A rows, * em, pack
    auto xposeA = [&](const f32x4& c0, const f32x4& c1,
                      const f32x4& c2, const f32x4& c3, bf16x8& A0, bf16x8& A1) {
        #pragma unroll
        for (int nt = 0; nt < 4; ++nt)
            #pragma unroll
            for (int r = 0; r < 4; ++r)
                tb[wv][4 * g + r][16 * nt + l] = acc[nt][r];
        __builtin_amdgcn_s_waitcnt(0xC07F);        // lgkmcnt(0) only, vmcnt open
        __builtin_amdgcn_wave_barrier();
        const float* rowp = &tb[wv][l][8 * g];
        f32x4 x0 = *(const f32x4*)rowp;
        f32x4 x1 = *(const f32x4*)(rowp + 4);
        f32x4 x2 = *(const f32x4*)(rowp + 32);
        f32x4 x3 = *(const f32x4*)(rowp + 36);
        #pragma unroll
        for (int d = 0; d < 4; ++d) {
            A0[d]     = (__bf16)(x0[d] * exp2f(c0[d] * LOG2E));
            A0[d + 4] = (__bf16)(x1[d] * exp2f(c1[d] * LOG2E));
            A1[d]     = (__bf16)(x2[d] * exp2f(c2[d] * LOG2E));
            A1[d + 4] = (__bf16)(x3[d] * exp2f(c3[d] * LOG2E));
        }
    };

    if (!bwd) {
        // y'_c = 1^T E d1 E d2 ... d(L-1) E  (em rows t0+1..t0+L-1; dL in phase2)
        { U4B t; t.u = make_uint4(0x3F803F80u, 0x3F803F80u, 0x3F803F80u, 0x3F803F80u);
          mfma8(t.b, t.b); }                       // tt=0: A = ones
        #pragma unroll
        for (int tt = 1; tt < L_; ++tt) {
            f32x4* q = em[tt - 1];
            bf16x8 A0, A1;
            xposeA(q[0], q[1], q[2], q[3], A0, A1);
            mfma8(A0, A1);
            if ((tt & 3) == 3) renorm();
        }
        float* yb = Ybuf + ((size_t)(b * WPB_ + wg) << 10);
        #pragma unroll
        for (int nt = 0; nt < 4; ++nt)
            *(f32x4*)(yb + ((nt * 64 + lane) << 2)) = acc[nt];   // coalesced
    } else {
        // z_c = E d1 E d2 ... E dL * 1, rows consumed descending (L..1)
        {   // i=0: A = em(row t0+L) (z = ones)
            f32x4* q = em[0];
            bf16x8 A0, A1;
            #pragma unroll
            for (int d = 0; d < 4; ++d) {
                A0[d]     = (__bf16)exp2f(q[0][d] * LOG2E);
                A0[d + 4] = (__bf16)exp2f(q[1][d] * LOG2E);
                A1[d]     = (__bf16)exp2f(q[2][d] * LOG2E);
                A1[d + 4] = (__bf16)exp2f(q[3][d] * LOG2E);
            }
            mfma8(A0, A1);
        }
        #pragma unroll
        for (int i = 1; i < L_; ++i) {
            f32x4* q = em[i];
            bf16x8 A0, A1;
            xposeA(q[0], q[1], q[2], q[3], A0, A1);
            mfma8(A0, A1);
            if ((i & 3) == 3) renorm();
        }
        float* zb = Zbuf + ((size_t)(b * WPB_ + wg) << 10);
        #pragma unroll
        for (int nt = 0; nt < 4; ++nt)
            *(f32x4*)(zb + ((nt * 64 + lane) << 2)) = acc[nt];   // coalesced
        if (l == 0) {
            #pragma unroll
            for (int r = 0; r < 4; ++r)
                Lz[b * CPB_ + 16 * wg + 4 * g + r] = (float)Lt[r];
        }
    }
}

// ---------------------------------------------------------------------------
// phase2: rank-1 recombination + per-batch reduce, one block per batch.
// UNCHANGED from R8 (kept as the controlled variable; with phase1 fast it
// will now show up in rocprof top-5 with its true duration).
// ---------------------------------------------------------------------------
__global__ __launch_bounds__(1024) void crf_phase2(
    const float* __restrict__ scores, const float* __restrict__ source,
    const float* __restrict__ sink,
    const float* __restrict__ Ybuf, const float* __restrict__ Zbuf,
    const float* __restrict__ Lz, float* __restrict__ out)
{
    __shared__ float part[16];
    const int b = blockIdx.x;
    const int wv = threadIdx.x >> 6, lane = threadIdx.x & 63;
    const int q = lane >> 4, l = lane & 15;
    float acc = 0.f;

    float esk[4];
    #pragma unroll
    for (int nt = 0; nt < 4; ++nt) esk[nt] = exp2f(sink[16 * nt + l] * LOG2E);

    for (int wg = wv; wg < WPB_; wg += 16) {
        const int bw = b * WPB_ + wg;
        const float* Yb = Ybuf + ((size_t)bw << 10);
        const float* Zb = Zbuf + ((size_t)bw << 10);
        f32x4 y[4], z[4];
        #pragma unroll
        for (int nt = 0; nt < 4; ++nt) {
            y[nt] = *(const f32x4*)(Yb + ((nt * 64 + lane) << 2));
            z[nt] = *(const f32x4*)(Zb + ((nt * 64 + lane) << 2));
        }
        // em rows (end of each of this lane's 4 chunks), state 16nt+l
        float E2[4][4];
        #pragma unroll
        for (int r = 0; r < 4; ++r) {
            int c = 16 * wg + 4 * q + r; int cc = c < NC_ ? c : NC_ - 1;
            const float* er = scores + ((size_t)b * T_ + (size_t)L_ * cc + L_) * S_;
            #pragma unroll
            for (int nt = 0; nt < 4; ++nt)
                E2[r][nt] = exp2f(er[16 * nt + l] * LOG2E);
        }
        // z_next for r==3: chunk (q+1,0), from quad q+1 (or next group if q==3)
        float zn3[4];
        #pragma unroll
        for (int nt = 0; nt < 4; ++nt) zn3[nt] = __shfl(z[nt][0], lane + 16, 64);
        if (q == 3 && wg + 1 < WPB_) {
            const float* Zn = Zbuf + (((size_t)bw + 1) << 10);
            #pragma unroll
            for (int nt = 0; nt < 4; ++nt) zn3[nt] = Zn[(nt * 64 + l) << 2];
        }

        #pragma unroll
        for (int r = 0; r < 4; ++r) {
            int c = 16 * wg + 4 * q + r;
            float p = 0.f, qs = 0.f;
            #pragma unroll
            for (int nt = 0; nt < 4; ++nt) {
                float zz = (r < 3) ? z[nt][r + 1] : zn3[nt];
                if (c == NC_ - 1) zz = esk[nt];
                float ye = y[nt][r] * E2[r][nt];
                p  += ye * zz;
                qs += ye;
            }
            #pragma unroll
            for (int m = 1; m <= 8; m <<= 1) {
                p  += __shfl_xor(p, m, 64);
                qs += __shfl_xor(qs, m, 64);
            }
            if (l == 0 && c < NC_)
                acc += log2f(p) - log2f(qs) + Lz[b * CPB_ + c];
        }
        if (wg == 0 && q == 0) {    // a0 . z_0 term (wave 0 only)
            float s0 = 0.f;
            #pragma unroll
            for (int nt = 0; nt < 4; ++nt) {
                float a0 = exp2f((source[16 * nt + l]
                                  + scores[(size_t)b * T_ * S_ + 16 * nt + l]) * LOG2E);
                s0 += a0 * z[nt][0];
            }
            #pragma unroll
            for (int m = 1; m <= 8; m <<= 1) s0 += __shfl_xor(s0, m, 64);
            if (l == 0) acc += log2f(s0);
        }
    }
    #pragma unroll
    for (int m = 32; m >= 1; m >>= 1) acc += __shfl_xor(acc, m, 64);
    if (lane == 0) part[wv] = acc;
    __syncthreads();
    if (threadIdx.x == 0) {
        float s = 0.f;
        #pragma unroll
        for (int i = 0; i < 16; ++i) s += part[i];
        out[b] = 0.6931471805599453f * s + 4.158883083359672f;  // ln2*log2Z + ln64
    }
}

extern "C" void kernel_launch(void* const* d_in, const int* in_sizes, int n_in,
                              void* d_out, int out_size, void* d_ws, size_t ws_size,
                              hipStream_t stream) {
    (void)in_sizes; (void)n_in; (void)out_size; (void)ws_size;
    const float* scores     = (const float*)d_in[0];
    const float* transition = (const float*)d_in[1];
    const float* source     = (const float*)d_in[2];
    const float* sink       = (const float*)d_in[3];
    float* out = (float*)d_out;

    float* Ybuf = (float*)d_ws;                          // 64*29*1024 f32 (7.3 MB)
    float* Zbuf = Ybuf + (size_t)B_ * WPB_ * 1024;       // 7.3 MB
    float* Lz   = Zbuf + (size_t)B_ * WPB_ * 1024;       // 116 KB

    hipLaunchKernelGGL(crf_phase1, dim3(2 * B_ * WPB_ / 4), dim3(256), 0, stream,
                       scores, transition, Ybuf, Zbuf, Lz);
    hipLaunchKernelGGL(crf_phase2, dim3(B_), dim3(1024), 0, stream,
                       scores, source, sink, Ybuf, Zbuf, Lz, out);
}

// Round 6
// 141.849 us; speedup vs baseline: 1.5177x; 1.2156x over previous
//
#include <hip/hip_runtime.h>
#include <cstdint>

// Linear-chain CRF log-partition, B=64, T=4096, S=64.
// R11 == R10 resubmit (bench infra failed twice; kernel audited for
// hang/fault paths: uniform barriers, in-bounds rows <= 4095, aligned f32x4,
// 0.5MB ws). Fused recombination design:
//  - R9 post-mortem: em[9] upfront burst is register-infeasible (144 VGPR) ->
//    allocator spilled (WRITE 127MB scratch). Revert to ring-3 (R6: 68 VGPR).
//  - Residue analysis: non-phase1 residue (49.6/79/84.5/87us) tracks phase2's
//    input footprint (ratio 1.58 = 14->22MB), stable across 3 phase2 shapes.
//    Fix: eliminate Y/Z materialization. One block = 32 chunks (2 fwd waves +
//    2 bwd waves, same chunks); acc -> block LDS; rank-1 recombination done
//    in-block (31 interior terms + a0). Only boundary data (zfirst, w, Lt,
//    partial; ~1KB/block) goes global; kernel2 (64 waves) closes 14 boundary
//    terms/batch + final reduce. ws 15MB -> 0.5MB.
//  - LDS 34KB/block, __launch_bounds__(256,4): 4 blocks/CU = 16 waves/CU.

#define B_    64
#define T_    4096
#define S_    64
#define L_    9
#define NC_   455                 // 455*9 = 4095 = T_-1
#define WPB_  30                  // chunk-groups per batch (30*16=480 chains)
#define BPB_  15                  // blocks per batch (32 chains per block)
#define LOG2E 1.44269504088896340736f

typedef float  f32x4  __attribute__((ext_vector_type(4)));
typedef __bf16 bf16x8 __attribute__((ext_vector_type(8)));
union U4B { uint4 u; bf16x8 b; };

__global__ __launch_bounds__(256, 4) void crf_fused(
    const float* __restrict__ scores,      // (B,T,S)
    const float* __restrict__ transition,  // (S,S) [from,to]
    const float* __restrict__ source, const float* __restrict__ sink,
    float* __restrict__ zfirst,            // (B*BPB, 64) raw zhat of chain 32j
    float* __restrict__ wbuf,              // (B*BPB, 64) y_last*em_end
    float* __restrict__ Ltlast,            // (B*BPB)     Ltz of chain 32j+31
    float* __restrict__ partial)           // (B*BPB)     per-block term sum
{
    __shared__ float tb[4][16][68];        // per-wave transpose slice
    __shared__ float ys[32][64];           // y'   (block chains 0..31)
    __shared__ float zs[32][64];           // zhat (block chains 0..31)
    __shared__ float Ltz[32];
    __shared__ float part[16];

    const int j  = blockIdx.x % BPB_;      // block within batch
    const int b  = blockIdx.x / BPB_;
    const int wv = threadIdx.x >> 6;       // 0,1 fwd; 2,3 bwd
    const bool bwd = wv >= 2;
    const int wg = 2 * j + (wv & 1);       // chunk-group handled by this wave
    const int lane = threadIdx.x & 63, g = lane >> 4, l = lane & 15;

    // A-side emission pointer: chain = local row l, states 8g.. contiguous
    int cl = 16 * wg + l; if (cl > NC_ - 1) cl = NC_ - 1;
    const float* ap = scores + ((size_t)b * T_ + L_ * cl + (bwd ? L_ : 0)) * S_ + 8 * g;

    f32x4 acc[4];
    f32x4 ring[3][4];                      // depth-3 prefetch ring (48 VGPRs)
    int   Lt[4] = {0, 0, 0, 0};

    auto ldq = [&](int idx, f32x4* q) {
        const float* p = ap + (ptrdiff_t)idx * S_;
        q[0] = *(const f32x4*)p;        q[1] = *(const f32x4*)(p + 4);
        q[2] = *(const f32x4*)(p + 32); q[3] = *(const f32x4*)(p + 36);
    };

    // ---- E fragments: fwd B[k][n]=exp(T[k][n]); bwd =exp(T[n][k])
    bf16x8 BE[2][4];
    #pragma unroll
    for (int kb = 0; kb < 2; ++kb)
    #pragma unroll
    for (int nt = 0; nt < 4; ++nt) {
        bf16x8 t;
        #pragma unroll
        for (int dd = 0; dd < 4; ++dd) {
            int k0 = 32 * kb + 8 * g + 2 * dd, n = 16 * nt + l;
            float e0, e1;
            if (!bwd) { e0 = transition[k0 * 64 + n]; e1 = transition[(k0 + 1) * 64 + n]; }
            else      { e0 = transition[n * 64 + k0]; e1 = transition[n * 64 + k0 + 1]; }
            t[2 * dd]     = (__bf16)exp2f(e0 * LOG2E);
            t[2 * dd + 1] = (__bf16)exp2f(e1 * LOG2E);
        }
        BE[kb][nt] = t;
    }

    auto mfma8 = [&](bf16x8 A0, bf16x8 A1) {
        #pragma unroll
        for (int nt = 0; nt < 4; ++nt) {
            f32x4 z4 = {0.f, 0.f, 0.f, 0.f};
            z4      = __builtin_amdgcn_mfma_f32_16x16x32_bf16(A0, BE[0][nt], z4, 0, 0, 0);
            acc[nt] = __builtin_amdgcn_mfma_f32_16x16x32_bf16(A1, BE[1][nt], z4, 0, 0, 0);
        }
    };
    auto renorm = [&]() {
        #pragma unroll
        for (int r = 0; r < 4; ++r) {
            float m = fmaxf(fmaxf(acc[0][r], acc[1][r]), fmaxf(acc[2][r], acc[3][r]));
            m = fmaxf(m, __shfl_xor(m, 1, 64));
            m = fmaxf(m, __shfl_xor(m, 2, 64));
            m = fmaxf(m, __shfl_xor(m, 4, 64));
            m = fmaxf(m, __shfl_xor(m, 8, 64));
            int ex = (int)(__float_as_uint(m) >> 23) - 127;
            float sc = __uint_as_float((unsigned)(127 - ex) << 23);   // exact 2^-ex
            Lt[r] += ex;
            #pragma unroll
            for (int nt = 0; nt < 4; ++nt) acc[nt][r] *= sc;
        }
    };
    // transpose acc (C: chain 4g+r, state 16nt+l) -> per-lane A rows, * em, pack
    auto xposeA = [&](const f32x4& c0, const f32x4& c1,
                      const f32x4& c2, const f32x4& c3, bf16x8& A0, bf16x8& A1) {
        #pragma unroll
        for (int nt = 0; nt < 4; ++nt)
            #pragma unroll
            for (int r = 0; r < 4; ++r)
                tb[wv][4 * g + r][16 * nt + l] = acc[nt][r];
        __builtin_amdgcn_s_waitcnt(0xC07F);        // lgkmcnt(0) only, vmcnt open
        __builtin_amdgcn_wave_barrier();
        const float* rowp = &tb[wv][l][8 * g];
        f32x4 x0 = *(const f32x4*)rowp;
        f32x4 x1 = *(const f32x4*)(rowp + 4);
        f32x4 x2 = *(const f32x4*)(rowp + 32);
        f32x4 x3 = *(const f32x4*)(rowp + 36);
        #pragma unroll
        for (int d = 0; d < 4; ++d) {
            A0[d]     = (__bf16)(x0[d] * exp2f(c0[d] * LOG2E));
            A0[d + 4] = (__bf16)(x1[d] * exp2f(c1[d] * LOG2E));
            A1[d]     = (__bf16)(x2[d] * exp2f(c2[d] * LOG2E));
            A1[d + 4] = (__bf16)(x3[d] * exp2f(c3[d] * LOG2E));
        }
    };

    if (!bwd) {
        // y'_c = 1^T E d1 E ... d8 E  (em rows t0+1..t0+8; d9 in recombination)
        ldq(1, ring[0]); ldq(2, ring[1]); ldq(3, ring[2]);
        { U4B t; t.u = make_uint4(0x3F803F80u, 0x3F803F80u, 0x3F803F80u, 0x3F803F80u);
          mfma8(t.b, t.b); }                       // tt=0: A = ones
        #pragma unroll
        for (int tt = 1; tt < L_; ++tt) {
            f32x4* q = ring[(tt - 1) % 3];
            f32x4 c0 = q[0], c1 = q[1], c2 = q[2], c3 = q[3];
            if (tt + 3 <= L_ - 1) ldq(tt + 3, ring[(tt - 1) % 3]);
            bf16x8 A0, A1;
            xposeA(c0, c1, c2, c3, A0, A1);
            mfma8(A0, A1);
            if ((tt & 3) == 3) renorm();
        }
        #pragma unroll
        for (int nt = 0; nt < 4; ++nt)
            #pragma unroll
            for (int r = 0; r < 4; ++r)
                ys[16 * (wv & 1) + 4 * g + r][16 * nt + l] = acc[nt][r];
    } else {
        // zhat_c = E d1 E ... E d9 * 1, rows consumed descending (9..1)
        ldq(0, ring[0]); ldq(-1, ring[1]); ldq(-2, ring[2]);
        {   // i=0: A = em(row t0+9) (z = ones)
            f32x4* q = ring[0];
            bf16x8 A0, A1;
            #pragma unroll
            for (int d = 0; d < 4; ++d) {
                A0[d]     = (__bf16)exp2f(q[0][d] * LOG2E);
                A0[d + 4] = (__bf16)exp2f(q[1][d] * LOG2E);
                A1[d]     = (__bf16)exp2f(q[2][d] * LOG2E);
                A1[d + 4] = (__bf16)exp2f(q[3][d] * LOG2E);
            }
            mfma8(A0, A1);
            ldq(-3, ring[0]);
        }
        #pragma unroll
        for (int i = 1; i < L_; ++i) {
            f32x4* q = ring[i % 3];
            f32x4 c0 = q[0], c1 = q[1], c2 = q[2], c3 = q[3];
            if (i + 3 <= L_ - 1) ldq(-(i + 3), ring[i % 3]);
            bf16x8 A0, A1;
            xposeA(c0, c1, c2, c3, A0, A1);
            mfma8(A0, A1);
            if ((i & 3) == 3) renorm();
        }
        #pragma unroll
        for (int nt = 0; nt < 4; ++nt)
            #pragma unroll
            for (int r = 0; r < 4; ++r)
                zs[16 * (wv & 1) + 4 * g + r][16 * nt + l] = acc[nt][r];
        if (l == 0) {
            #pragma unroll
            for (int r = 0; r < 4; ++r)
                Ltz[16 * (wv & 1) + 4 * g + r] = (float)Lt[r];
        }
    }
    __syncthreads();

    // ---- export zfirst (raw zhat of block chain 0); its Ltz[0] is added at
    // chain 32j's own term below (mirrors original phase2 semantics).
    if (wv == 0) zfirst[((size_t)(b * BPB_ + j)) * 64 + lane] = zs[0][lane];

    // ---- in-block rank-1 recombination: quad (wv,q) handles chains
    // m = 8*wv + 2*q + {0,1}; lane l covers states l, l+16, l+32, l+48.
    const int q = g;
    float myterm = 0.f;
    #pragma unroll
    for (int h = 0; h < 2; ++h) {
        const int m = 8 * wv + 2 * q + h;
        const int c = 32 * j + m;
        const int cc = c < NC_ ? c : NC_ - 1;
        const float* er = scores + ((size_t)b * T_ + (size_t)L_ * (cc + 1)) * S_;
        float ye[4], pp = 0.f, qs = 0.f;
        #pragma unroll
        for (int k = 0; k < 4; ++k) {
            ye[k] = ys[m][16 * k + l] * exp2f(er[16 * k + l] * LOG2E);
            float zz = (c == NC_ - 1) ? exp2f(sink[16 * k + l] * LOG2E)
                                      : zs[(m + 1) & 31][16 * k + l];
            pp += ye[k] * zz;
            qs += ye[k];
        }
        #pragma unroll
        for (int mm = 1; mm <= 8; mm <<= 1) {
            pp += __shfl_xor(pp, mm, 64);
            qs += __shfl_xor(qs, mm, 64);
        }
        if (m == 31) {
            if (c < NC_ - 1) {   // real boundary -> defer to kernel2
                #pragma unroll
                for (int k = 0; k < 4; ++k)
                    wbuf[((size_t)(b * BPB_ + j)) * 64 + 16 * k + l] = ye[k];
                if (l == 0) Ltlast[b * BPB_ + j] = Ltz[31];
            }
        } else if (c < NC_ && l == 0) {
            myterm += log2f(pp) - log2f(qs) + Ltz[m];
        }
    }
    // a0 . zhat_0 term (first block of batch only)
    if (j == 0 && wv == 0 && q == 0) {
        float s0 = 0.f;
        #pragma unroll
        for (int k = 0; k < 4; ++k) {
            float a0 = exp2f((source[16 * k + l]
                              + scores[(size_t)b * T_ * S_ + 16 * k + l]) * LOG2E);
            s0 += a0 * zs[0][16 * k + l];
        }
        #pragma unroll
        for (int mm = 1; mm <= 8; mm <<= 1) s0 += __shfl_xor(s0, mm, 64);
        if (l == 0) myterm += log2f(s0);
    }
    if (l == 0) part[4 * wv + q] = myterm;
    __syncthreads();
    if (threadIdx.x == 0) {
        float s = 0.f;
        #pragma unroll
        for (int i = 0; i < 16; ++i) s += part[i];
        partial[b * BPB_ + j] = s;
    }
}

// ---------------------------------------------------------------------------
// kernel2: one wave per batch. 14 boundary terms (chain 32j+31 needs zfirst of
// block j+1) + sum of the 15 block partials + final transform.
// ---------------------------------------------------------------------------
__global__ __launch_bounds__(64) void crf_reduce(
    const float* __restrict__ zfirst, const float* __restrict__ wbuf,
    const float* __restrict__ Ltlast, const float* __restrict__ partial,
    float* __restrict__ out)
{
    const int b = blockIdx.x;
    const int lane = threadIdx.x;
    float acc = 0.f;
    for (int jj = 0; jj < BPB_ - 1; ++jj) {
        float w  = wbuf  [((size_t)(b * BPB_ + jj)) * 64 + lane];
        float zf = zfirst[((size_t)(b * BPB_ + jj + 1)) * 64 + lane];
        float pp = w * zf, qs = w;
        #pragma unroll
        for (int mm = 1; mm <= 32; mm <<= 1) {
            pp += __shfl_xor(pp, mm, 64);
            qs += __shfl_xor(qs, mm, 64);
        }
        if (lane == 0) acc += log2f(pp) - log2f(qs) + Ltlast[b * BPB_ + jj];
    }
    if (lane == 0) {
        float s = acc;
        for (int jj = 0; jj < BPB_; ++jj) s += partial[b * BPB_ + jj];
        out[b] = 0.6931471805599453f * s + 4.158883083359672f;  // ln2*log2Z + ln64
    }
}

extern "C" void kernel_launch(void* const* d_in, const int* in_sizes, int n_in,
                              void* d_out, int out_size, void* d_ws, size_t ws_size,
                              hipStream_t stream) {
    (void)in_sizes; (void)n_in; (void)out_size; (void)ws_size;
    const float* scores     = (const float*)d_in[0];
    const float* transition = (const float*)d_in[1];
    const float* source     = (const float*)d_in[2];
    const float* sink       = (const float*)d_in[3];
    float* out = (float*)d_out;

    float* zfirst  = (float*)d_ws;                        // 64*15*64 f32 = 245KB
    float* wbuf    = zfirst + (size_t)B_ * BPB_ * 64;     // 245KB
    float* Ltlast  = wbuf   + (size_t)B_ * BPB_ * 64;     // 3.8KB
    float* partial = Ltlast + (size_t)B_ * BPB_;          // 3.8KB

    hipLaunchKernelGGL(crf_fused, dim3(B_ * BPB_), dim3(256), 0, stream,
                       scores, transition, source, sink,
                       zfirst, wbuf, Ltlast, partial);
    hipLaunchKernelGGL(crf_reduce, dim3(B_), dim3(64), 0, stream,
                       zfirst, wbuf, Ltlast, partial, out);
}